// Round 9
// baseline (7076.728 us; speedup 1.0000x reference)
//
#include <hip/hip_runtime.h>
#include <math.h>

// LSTMPredictor: B=2048 rows, 3x LSTMCell(H=50), P=17, T=512 + 32 future steps.
// fp32 buffers (runtime-sniffed, bf16 fallback kept).
//
// Evidence ledger:
//   R0-R7: VALU path now healthy (R7: VGPR=120, real issue ~3.5k cyc/SIMD/step
//   == hand count). But step = ~15k cycles: ~75% is barrier/latency dead time
//   (1 block/CU, 2 waves/SIMD, 6 lockstep barriers/step; nothing co-resident
//   to issue during drains).
// R8: TWO independent blocks per CU. M=8->4 rows/block, grid 256->512.
//   Block A's barrier drains overlap block B's compute (m114 co-scheduling).
//   Thread = (2 gates, K-fifth), 500/512 active; weights 108 fl, acc 8,
//   ~125 live regs; __launch_bounds__(512,4) caps at 128 so both blocks fit
//   (16 waves/CU = 4/SIMD). LDS ~25KB/block. Gates: Occupancy must hit ~48%,
//   FETCH must stay ~36MB (spill tripwire).

#define BATCH    2048
#define PP       17
#define HH       50
#define GG       200      // 4*H
#define MROWS    4
#define NQ       5        // K split into fifths
#define NTHREADS 512
#define NACTIVE  500      // 100 gate-pairs x 5 fifths
#define NBLOCKS  (BATCH / MROWS)   // 512 = 2 blocks per CU
#define TQ1      14       // cell1 K=68 (x17 + h50 + pad) -> 5*14=70
#define TQ2      20       // cell2 K=100 exact
#define TQ3      20       // cell3 K=100 exact

__device__ __forceinline__ float bf2f(unsigned short u) {
    unsigned int i = ((unsigned int)u) << 16;
    float f; __builtin_memcpy(&f, &i, 4); return f;
}
__device__ __forceinline__ unsigned short f2bf(float f) {
    unsigned int i; __builtin_memcpy(&i, &f, 4);
    return (unsigned short)((i + 0x7fffu + ((i >> 16) & 1u)) >> 16);
}
__device__ __forceinline__ float ldin(const void* p, long i, bool f32) {
    return f32 ? ((const float*)p)[i] : bf2f(((const unsigned short*)p)[i]);
}
// saturation-safe fast sigmoid/tanh (v_exp_f32 + v_rcp_f32)
__device__ __forceinline__ float fsig(float x) {
    float t = exp2f(-1.44269504089f * x);          // +inf at x->-inf, 0 at x->+inf
    return __builtin_amdgcn_rcpf(1.0f + t);        // 0 / 1 at the limits
}
__device__ __forceinline__ float ftanh(float x) {
    float t = exp2f(2.88539008178f * x);           // e^(2x)
    return 1.0f - 2.0f * __builtin_amdgcn_rcpf(t + 1.0f);   // -1 / +1 at the limits
}

// ---- dtype sniffer: bf16 weights decode to |v|<=0.142; fp32-as-bf16 gives junk ----
extern "C" __global__ void sniff_dtype(const unsigned short* __restrict__ w,
                                       int* __restrict__ flag) {
    int lane = threadIdx.x;
    bool bad = false;
#pragma unroll
    for (int t = 0; t < 4; ++t) {
        float v = bf2f(w[lane * 4 + t]);
        bad |= !(fabsf(v) <= 1.0f);
    }
    unsigned long long m = __ballot(bad);
    if (lane == 0) flag[0] = (m != 0ULL) ? 1 : 0;   // 1 => fp32 buffers
}

// gate phase: thread (g2, q) accumulates the K-fifth partial of gates
// {2g2, 2g2+1} for all 4 rows. 1 b128 state read per k feeds 8 fmafs.
template <int TQ>
__device__ __forceinline__ void gate_phase(const float* __restrict__ S,
                                           float* __restrict__ gb,
                                           const float (&w)[2][TQ],
                                           int srow, int g2, int q, bool active) {
    if (active) {
        float a[2][4] = {};
        const float4* Sp = (const float4*)(S + (srow + q * TQ) * MROWS);
#pragma unroll
        for (int t = 0; t < TQ; ++t) {
            float4 ro = Sp[t];             // rows m=0..3 of state k (broadcast)
#pragma unroll
            for (int e = 0; e < 2; ++e) {
                float wv = w[e][t];
                a[e][0] = fmaf(wv, ro.x, a[e][0]); a[e][1] = fmaf(wv, ro.y, a[e][1]);
                a[e][2] = fmaf(wv, ro.z, a[e][2]); a[e][3] = fmaf(wv, ro.w, a[e][3]);
            }
        }
        // gb[q][m][gate]: 2 adjacent gates -> one float2 store per row
#pragma unroll
        for (int m = 0; m < 4; ++m) {
            float2 v; v.x = a[0][m]; v.y = a[1][m];
            *(float2*)(gb + (q * MROWS + m) * GG + 2 * g2) = v;
        }
    }
}

__device__ __forceinline__ void lstm_update(float* __restrict__ S,
                                            const float* __restrict__ gb,
                                            const float* __restrict__ bs,
                                            float& c, int hrow, int tid) {
    // caller guards tid < 200;  m = tid&3 (conflict-free h write), j = tid>>2
    int m = tid & 3;
    int j = tid >> 2;
    float ii = bs[j], ff = bs[50 + j], gg = bs[100 + j], oo = bs[150 + j];
#pragma unroll
    for (int q = 0; q < NQ; ++q) {
        // addr%32 = (4m... (200m+j))%32 = (8m+j)%32-like -> <=2-way (free)
        const float* b = gb + (q * MROWS + m) * GG;
        ii += b[j]; ff += b[50 + j]; gg += b[100 + j]; oo += b[150 + j];
    }
    float cn = fsig(ff) * c + fsig(ii) * ftanh(gg);
    c = cn;
    S[(hrow + j) * MROWS + m] = fsig(oo) * ftanh(cn);   // addr = hrow*4 + tid
}

extern "C" __global__ void __launch_bounds__(NTHREADS, 4)
lstm_persistent(const void* __restrict__ x,
                const void* __restrict__ wih1, const void* __restrict__ whh1,
                const void* __restrict__ bih1, const void* __restrict__ bhh1,
                const void* __restrict__ wih2, const void* __restrict__ whh2,
                const void* __restrict__ bih2, const void* __restrict__ bhh2,
                const void* __restrict__ wih3, const void* __restrict__ whh3,
                const void* __restrict__ bih3, const void* __restrict__ bhh3,
                const void* __restrict__ wlin, const void* __restrict__ blin,
                void* __restrict__ out, const int* __restrict__ flag,
                int T, int steps)
{
    const int tid = threadIdx.x;
    __shared__ float S[167 * MROWS];        // 0..16 x | 17..66 h1 | 67..116 h2 | 117..166 h3
    __shared__ float gb[NQ * MROWS * GG];   // [fifth][m][gate]  (16 KB)
    __shared__ float WLt[50 * PP];          // W_lin^T
    __shared__ float bs1[GG], bs2[GG], bs3[GG], bl[PP];

    const bool f32 = (flag[0] != 0);

    const int q  = tid / 100;               // K-fifth (<=2 distinct q per wave)
    const int g2 = tid - q * 100;           // gate-pair 0..99
    const bool active = (tid < NACTIVE);    // 500 of 512

    // ---- per-thread register weights (fp32, full precision): 108 floats ----
    float w1[2][TQ1], w2[2][TQ2], w3[2][TQ3];
    if (active) {
#pragma unroll
        for (int e = 0; e < 2; ++e) {
            const int g = 2 * g2 + e;
#pragma unroll
            for (int t = 0; t < TQ1; ++t) {          // cell1 K=68 (rows 68,69 zero)
                int k = q * TQ1 + t;
                w1[e][t] = (k < 17) ? ldin(wih1, (long)g * 17 + k, f32)
                         : (k < 67) ? ldin(whh1, (long)g * 50 + (k - 17), f32)
                                    : 0.0f;
            }
#pragma unroll
            for (int t = 0; t < TQ2; ++t) {          // cell2 K=100
                int k = q * TQ2 + t;
                w2[e][t] = (k < 50) ? ldin(wih2, (long)g * 50 + k, f32)
                                    : ldin(whh2, (long)g * 50 + (k - 50), f32);
            }
#pragma unroll
            for (int t = 0; t < TQ3; ++t) {          // cell3 K=100
                int k = q * TQ3 + t;
                w3[e][t] = (k < 50) ? ldin(wih3, (long)g * 50 + k, f32)
                                    : ldin(whh3, (long)g * 50 + (k - 50), f32);
            }
        }
    }

    // ---- stage biases, W_lin^T, zero h-state, preload x(step 0) ----
    if (tid < GG) {
        bs1[tid] = ldin(bih1, tid, f32) + ldin(bhh1, tid, f32);
        bs2[tid] = ldin(bih2, tid, f32) + ldin(bhh2, tid, f32);
        bs3[tid] = ldin(bih3, tid, f32) + ldin(bhh3, tid, f32);
    } else if (tid < GG + PP) {
        bl[tid - GG] = ldin(blin, tid - GG, f32);
    }
    for (int i = tid; i < 50 * PP; i += NTHREADS) {
        int k = i / PP, p = i - k * PP;
        WLt[i] = ldin(wlin, (long)p * 50 + k, f32);
    }
    for (int i = tid; i < 150 * MROWS; i += NTHREADS) S[17 * MROWS + i] = 0.0f; // h1,h2,h3 = 0

    const long rowBase = (long)blockIdx.x * MROWS;
    const long xStride = (long)T * PP;
    if (tid < PP * MROWS) {
        int m = tid / PP, p = tid - (tid / PP) * PP;
        S[p * MROWS + m] = ldin(x, (rowBase + m) * xStride + p, f32);
    }
    float c1 = 0.0f, c2 = 0.0f, c3 = 0.0f;
    __syncthreads();

    const long outStride = (long)steps * PP;
    for (int s = 0; s < steps; ++s) {
        gate_phase<TQ1>(S, gb, w1, 0, g2, q, active);           // cell1: [x|h1]
        __syncthreads();
        if (tid < 200) lstm_update(S, gb, bs1, c1, 17, tid);    // write h1
        __syncthreads();
        gate_phase<TQ2>(S, gb, w2, 17, g2, q, active);          // cell2: [h1|h2]
        __syncthreads();
        if (tid < 200) lstm_update(S, gb, bs2, c2, 67, tid);    // write h2
        __syncthreads();
        gate_phase<TQ3>(S, gb, w3, 67, g2, q, active);          // cell3: [h2|h3]
        __syncthreads();
        if (tid < 200) lstm_update(S, gb, bs3, c3, 117, tid);   // write h3
        __syncthreads();
        // ---- linear head + output + next input (feedback or global x) ----
        if (tid < PP * MROWS) {                                 // 68 threads
            int m = tid / PP, p = tid - (tid / PP) * PP;
            float acc = bl[p];
#pragma unroll
            for (int k = 0; k < 50; ++k)
                acc = fmaf(WLt[k * PP + p], S[(117 + k) * MROWS + m], acc);
            long oi = (rowBase + m) * outStride + (long)s * PP + p;
            if (f32) ((float*)out)[oi] = acc;
            else     ((unsigned short*)out)[oi] = f2bf(acc);
            if (s + 1 >= T && s + 1 < steps)                    // autoregressive feedback
                S[p * MROWS + m] = acc;
        } else if (tid >= 256 && tid < 256 + PP * MROWS) {      // 68 threads
            int u = tid - 256;
            int m = u / PP, p = u - (u / PP) * PP;
            if (s + 1 < T)                                      // prefetch next x chunk
                S[p * MROWS + m] = ldin(x, (rowBase + m) * xStride + (long)(s + 1) * PP + p, f32);
        }
        __syncthreads();
    }
}

extern "C" void kernel_launch(void* const* d_in, const int* in_sizes, int n_in,
                              void* d_out, int out_size, void* d_ws, size_t ws_size,
                              hipStream_t stream) {
    (void)ws_size; (void)n_in;
    int* flag = (int*)d_ws;

    const int T     = in_sizes[0] / (BATCH * PP);   // 512
    const int steps = out_size / (BATCH * PP);      // 544

    sniff_dtype<<<1, 64, 0, stream>>>((const unsigned short*)d_in[1], flag);

    lstm_persistent<<<NBLOCKS, NTHREADS, 0, stream>>>(
        d_in[0],
        d_in[1], d_in[2], d_in[3], d_in[4],
        d_in[5], d_in[6], d_in[7], d_in[8],
        d_in[9], d_in[10], d_in[11], d_in[12],
        d_in[13], d_in[14],
        d_out, flag, T, steps);
}

// Round 10
// 3649.254 us; speedup vs baseline: 1.9392x; 1.9392x over previous
//
#include <hip/hip_runtime.h>
#include <math.h>

// LSTMPredictor: B=2048 rows, 3x LSTMCell(H=50), P=17, T=512 + 32 future steps.
// fp32 buffers (runtime-sniffed, bf16 fallback kept).
//
// Evidence ledger:
//   R7 (M=8, 512thr, __launch_bounds__(512,2)): VGPR=120 healthy, 3163 us,
//     but grid 256 = 1 block/CU -> ~75% of step is barrier/latency dead time.
//   R8 (M=4, grid 512, __launch_bounds__(512,4)): budget crushed to 64 VGPR,
//     weights spilled (FETCH 23.6 GB), 7.1 ms. Structure untested.
// R9: R8 geometry + R7's qualifier. __launch_bounds__'s 2nd arg is the
//   MINIMUM-occupancy budget declaration, not a residency cap: (512,2) gives
//   budget 256, allocator lands ~120, and at 120 regs the HW fits 4 waves/SIMD
//   = TWO independent 8-wave blocks per CU (LDS 2x24.5KB << 160KB). Block A's
//   barrier drains overlap block B's compute (m114 co-scheduling).
//   Gates: VGPR <= 128; FETCH ~36MB; Occupancy ~48%.

#define BATCH    2048
#define PP       17
#define HH       50
#define GG       200      // 4*H
#define MROWS    4
#define NQ       5        // K split into fifths
#define NTHREADS 512
#define NACTIVE  500      // 100 gate-pairs x 5 fifths
#define NBLOCKS  (BATCH / MROWS)   // 512 = 2 blocks per CU
#define TQ1      14       // cell1 K=68 (x17 + h50 + pad) -> 5*14=70
#define TQ2      20       // cell2 K=100 exact
#define TQ3      20       // cell3 K=100 exact

__device__ __forceinline__ float bf2f(unsigned short u) {
    unsigned int i = ((unsigned int)u) << 16;
    float f; __builtin_memcpy(&f, &i, 4); return f;
}
__device__ __forceinline__ unsigned short f2bf(float f) {
    unsigned int i; __builtin_memcpy(&i, &f, 4);
    return (unsigned short)((i + 0x7fffu + ((i >> 16) & 1u)) >> 16);
}
__device__ __forceinline__ float ldin(const void* p, long i, bool f32) {
    return f32 ? ((const float*)p)[i] : bf2f(((const unsigned short*)p)[i]);
}
// saturation-safe fast sigmoid/tanh (v_exp_f32 + v_rcp_f32)
__device__ __forceinline__ float fsig(float x) {
    float t = exp2f(-1.44269504089f * x);          // +inf at x->-inf, 0 at x->+inf
    return __builtin_amdgcn_rcpf(1.0f + t);        // 0 / 1 at the limits
}
__device__ __forceinline__ float ftanh(float x) {
    float t = exp2f(2.88539008178f * x);           // e^(2x)
    return 1.0f - 2.0f * __builtin_amdgcn_rcpf(t + 1.0f);   // -1 / +1 at the limits
}

// ---- dtype sniffer: bf16 weights decode to |v|<=0.142; fp32-as-bf16 gives junk ----
extern "C" __global__ void sniff_dtype(const unsigned short* __restrict__ w,
                                       int* __restrict__ flag) {
    int lane = threadIdx.x;
    bool bad = false;
#pragma unroll
    for (int t = 0; t < 4; ++t) {
        float v = bf2f(w[lane * 4 + t]);
        bad |= !(fabsf(v) <= 1.0f);
    }
    unsigned long long m = __ballot(bad);
    if (lane == 0) flag[0] = (m != 0ULL) ? 1 : 0;   // 1 => fp32 buffers
}

// gate phase: thread (g2, q) accumulates the K-fifth partial of gates
// {2g2, 2g2+1} for all 4 rows. 1 b128 state read per k feeds 8 fmafs.
template <int TQ>
__device__ __forceinline__ void gate_phase(const float* __restrict__ S,
                                           float* __restrict__ gb,
                                           const float (&w)[2][TQ],
                                           int srow, int g2, int q, bool active) {
    if (active) {
        float a[2][4] = {};
        const float4* Sp = (const float4*)(S + (srow + q * TQ) * MROWS);
#pragma unroll
        for (int t = 0; t < TQ; ++t) {
            float4 ro = Sp[t];             // rows m=0..3 of state k (broadcast)
#pragma unroll
            for (int e = 0; e < 2; ++e) {
                float wv = w[e][t];
                a[e][0] = fmaf(wv, ro.x, a[e][0]); a[e][1] = fmaf(wv, ro.y, a[e][1]);
                a[e][2] = fmaf(wv, ro.z, a[e][2]); a[e][3] = fmaf(wv, ro.w, a[e][3]);
            }
        }
        // gb[q][m][gate]: 2 adjacent gates -> one float2 store per row
#pragma unroll
        for (int m = 0; m < 4; ++m) {
            float2 v; v.x = a[0][m]; v.y = a[1][m];
            *(float2*)(gb + (q * MROWS + m) * GG + 2 * g2) = v;
        }
    }
}

__device__ __forceinline__ void lstm_update(float* __restrict__ S,
                                            const float* __restrict__ gb,
                                            const float* __restrict__ bs,
                                            float& c, int hrow, int tid) {
    // caller guards tid < 200;  m = tid&3 (conflict-free h write), j = tid>>2
    int m = tid & 3;
    int j = tid >> 2;
    float ii = bs[j], ff = bs[50 + j], gg = bs[100 + j], oo = bs[150 + j];
#pragma unroll
    for (int q = 0; q < NQ; ++q) {
        // lane addr%32 spreads across banks <=2-way (free)
        const float* b = gb + (q * MROWS + m) * GG;
        ii += b[j]; ff += b[50 + j]; gg += b[100 + j]; oo += b[150 + j];
    }
    float cn = fsig(ff) * c + fsig(ii) * ftanh(gg);
    c = cn;
    S[(hrow + j) * MROWS + m] = fsig(oo) * ftanh(cn);   // addr = hrow*4 + tid
}

extern "C" __global__ void __launch_bounds__(NTHREADS, 2)
lstm_persistent(const void* __restrict__ x,
                const void* __restrict__ wih1, const void* __restrict__ whh1,
                const void* __restrict__ bih1, const void* __restrict__ bhh1,
                const void* __restrict__ wih2, const void* __restrict__ whh2,
                const void* __restrict__ bih2, const void* __restrict__ bhh2,
                const void* __restrict__ wih3, const void* __restrict__ whh3,
                const void* __restrict__ bih3, const void* __restrict__ bhh3,
                const void* __restrict__ wlin, const void* __restrict__ blin,
                void* __restrict__ out, const int* __restrict__ flag,
                int T, int steps)
{
    const int tid = threadIdx.x;
    __shared__ float S[167 * MROWS];        // 0..16 x | 17..66 h1 | 67..116 h2 | 117..166 h3
    __shared__ float gb[NQ * MROWS * GG];   // [fifth][m][gate]  (16 KB)
    __shared__ float WLt[50 * PP];          // W_lin^T
    __shared__ float bs1[GG], bs2[GG], bs3[GG], bl[PP];

    const bool f32 = (flag[0] != 0);

    const int q  = tid / 100;               // K-fifth (<=2 distinct q per wave)
    const int g2 = tid - q * 100;           // gate-pair 0..99
    const bool active = (tid < NACTIVE);    // 500 of 512

    // ---- per-thread register weights (fp32, full precision): 108 floats ----
    float w1[2][TQ1], w2[2][TQ2], w3[2][TQ3];
    if (active) {
#pragma unroll
        for (int e = 0; e < 2; ++e) {
            const int g = 2 * g2 + e;
#pragma unroll
            for (int t = 0; t < TQ1; ++t) {          // cell1 K=68 (rows 68,69 zero)
                int k = q * TQ1 + t;
                w1[e][t] = (k < 17) ? ldin(wih1, (long)g * 17 + k, f32)
                         : (k < 67) ? ldin(whh1, (long)g * 50 + (k - 17), f32)
                                    : 0.0f;
            }
#pragma unroll
            for (int t = 0; t < TQ2; ++t) {          // cell2 K=100
                int k = q * TQ2 + t;
                w2[e][t] = (k < 50) ? ldin(wih2, (long)g * 50 + k, f32)
                                    : ldin(whh2, (long)g * 50 + (k - 50), f32);
            }
#pragma unroll
            for (int t = 0; t < TQ3; ++t) {          // cell3 K=100
                int k = q * TQ3 + t;
                w3[e][t] = (k < 50) ? ldin(wih3, (long)g * 50 + k, f32)
                                    : ldin(whh3, (long)g * 50 + (k - 50), f32);
            }
        }
    }

    // ---- stage biases, W_lin^T, zero h-state, preload x(step 0) ----
    if (tid < GG) {
        bs1[tid] = ldin(bih1, tid, f32) + ldin(bhh1, tid, f32);
        bs2[tid] = ldin(bih2, tid, f32) + ldin(bhh2, tid, f32);
        bs3[tid] = ldin(bih3, tid, f32) + ldin(bhh3, tid, f32);
    } else if (tid < GG + PP) {
        bl[tid - GG] = ldin(blin, tid - GG, f32);
    }
    for (int i = tid; i < 50 * PP; i += NTHREADS) {
        int k = i / PP, p = i - k * PP;
        WLt[i] = ldin(wlin, (long)p * 50 + k, f32);
    }
    for (int i = tid; i < 150 * MROWS; i += NTHREADS) S[17 * MROWS + i] = 0.0f; // h1,h2,h3 = 0

    const long rowBase = (long)blockIdx.x * MROWS;
    const long xStride = (long)T * PP;
    if (tid < PP * MROWS) {
        int m = tid / PP, p = tid - (tid / PP) * PP;
        S[p * MROWS + m] = ldin(x, (rowBase + m) * xStride + p, f32);
    }
    float c1 = 0.0f, c2 = 0.0f, c3 = 0.0f;
    __syncthreads();

    const long outStride = (long)steps * PP;
    for (int s = 0; s < steps; ++s) {
        gate_phase<TQ1>(S, gb, w1, 0, g2, q, active);           // cell1: [x|h1]
        __syncthreads();
        if (tid < 200) lstm_update(S, gb, bs1, c1, 17, tid);    // write h1
        __syncthreads();
        gate_phase<TQ2>(S, gb, w2, 17, g2, q, active);          // cell2: [h1|h2]
        __syncthreads();
        if (tid < 200) lstm_update(S, gb, bs2, c2, 67, tid);    // write h2
        __syncthreads();
        gate_phase<TQ3>(S, gb, w3, 67, g2, q, active);          // cell3: [h2|h3]
        __syncthreads();
        if (tid < 200) lstm_update(S, gb, bs3, c3, 117, tid);   // write h3
        __syncthreads();
        // ---- linear head + output + next input (feedback or global x) ----
        if (tid < PP * MROWS) {                                 // 68 threads
            int m = tid / PP, p = tid - (tid / PP) * PP;
            float acc = bl[p];
#pragma unroll
            for (int k = 0; k < 50; ++k)
                acc = fmaf(WLt[k * PP + p], S[(117 + k) * MROWS + m], acc);
            long oi = (rowBase + m) * outStride + (long)s * PP + p;
            if (f32) ((float*)out)[oi] = acc;
            else     ((unsigned short*)out)[oi] = f2bf(acc);
            if (s + 1 >= T && s + 1 < steps)                    // autoregressive feedback
                S[p * MROWS + m] = acc;
        } else if (tid >= 256 && tid < 256 + PP * MROWS) {      // 68 threads
            int u = tid - 256;
            int m = u / PP, p = u - (u / PP) * PP;
            if (s + 1 < T)                                      // prefetch next x chunk
                S[p * MROWS + m] = ldin(x, (rowBase + m) * xStride + (long)(s + 1) * PP + p, f32);
        }
        __syncthreads();
    }
}

extern "C" void kernel_launch(void* const* d_in, const int* in_sizes, int n_in,
                              void* d_out, int out_size, void* d_ws, size_t ws_size,
                              hipStream_t stream) {
    (void)ws_size; (void)n_in;
    int* flag = (int*)d_ws;

    const int T     = in_sizes[0] / (BATCH * PP);   // 512
    const int steps = out_size / (BATCH * PP);      // 544

    sniff_dtype<<<1, 64, 0, stream>>>((const unsigned short*)d_in[1], flag);

    lstm_persistent<<<NBLOCKS, NTHREADS, 0, stream>>>(
        d_in[0],
        d_in[1], d_in[2], d_in[3], d_in[4],
        d_in[5], d_in[6], d_in[7], d_in[8],
        d_in[9], d_in[10], d_in[11], d_in[12],
        d_in[13], d_in[14],
        d_out, flag, T, steps);
}